// Round 17
// baseline (127.517 us; speedup 1.0000x reference)
//
#include <hip/hip_runtime.h>
#include <hip/hip_bf16.h>

#define DIM 768
#define NE 64
#define NFRQ 2048
#define NB 32
#define HALF 384                // computed quadrant extent (y,x in [0,384))
#define KROW 1536               // BT per-x row elems: [ReP|-ImP|ReM|-ImM] x 384
#define KG 768                  // GEMM K per parity (384 cos + 384 sin)
#define TWO_PI 6.283185307179586f
#define INV768 (1.0f / 768.0f)
#define SCALE (300.0f / (float)(DIM * DIM))   // ALPHA / (dim*dim), folded into values

typedef __attribute__((ext_vector_type(8))) short bf16x8;   // 8 bf16 (4 VGPRs)
typedef __attribute__((ext_vector_type(4))) float f32x4;    // MFMA accumulator

// ---------------------------------------------------------------------------
// Kernel A "prep" (one launch, 3 roles by blockIdx)  [unchanged]
// ---------------------------------------------------------------------------
__global__ __launch_bounds__(256) void prep_kernel(const float* __restrict__ cls,
                                                   const float* __restrict__ W,
                                                   const float* __restrict__ bias,
                                                   const float* __restrict__ coeff,
                                                   const int* __restrict__ lidx,
                                                   int* __restrict__ row_start,
                                                   float2* __restrict__ s_cv,
                                                   __hip_bfloat16* __restrict__ A,
                                                   float2* __restrict__ T2) {
  int bid = blockIdx.x;
  int tid = threadIdx.x;

  if (bid >= 32 + 2 * 192) {          // ---- T2 rows ----
    int c = bid - (32 + 2 * 192);     // 0..767
    for (int x = tid; x < HALF; x += 256) {
      float prod = (float)(c * x);    // < 2^24, exact
      float f, sn, cs;
      float rev = prod * INV768;
      asm("v_fract_f32 %0, %1" : "=v"(f) : "v"(rev));
      asm("v_sin_f32 %0, %1" : "=v"(sn) : "v"(f));
      asm("v_cos_f32 %0, %1" : "=v"(cs) : "v"(f));
      T2[(size_t)c * HALF + x] = make_float2(cs, -sn);
    }
    return;
  }
  if (bid >= 32) {                    // ---- A twiddle rows (parity layout) ----
    int idx = bid - 32;               // 0..383 ; row idx = par*192 + t
    int y = 2 * (idx % 192) + (idx / 192);
    if (tid < 96) {
      int r0 = tid * 4;
      union { __hip_bfloat16 h[4]; ushort4 v; } uc, us;
#pragma unroll
      for (int j = 0; j < 4; ++j) {
        int m = (y * (r0 + j)) % DIM;
        float s, c;
        sincosf((TWO_PI / (float)DIM) * (float)m, &s, &c);
        uc.h[j] = __float2bfloat16(c);
        us.h[j] = __float2bfloat16(s);
      }
      *(ushort4*)(A + (size_t)idx * KG + r0)        = uc.v;
      *(ushort4*)(A + (size_t)idx * KG + HALF + r0) = us.v;
    }
    return;
  }

  // ---- router + build, batch b = bid ----
  int b = bid;
  __shared__ int cnt[DIM];
  __shared__ int base[DIM];
  __shared__ int wsum[4];
  __shared__ int sel_i[2];
  __shared__ float sel_f[2];
  float* part   = (float*)cnt;
  float* logits = (float*)base;

  {
    int e = tid & 63, q = tid >> 6;
    const float* c = cls + b * DIM + q * 192;
    const float* w = W + e * DIM + q * 192;
    float acc = 0.f;
#pragma unroll 4
    for (int i = 0; i < 192; i += 4) {
      float4 cv4 = *(const float4*)(c + i);
      float4 wv4 = *(const float4*)(w + i);
      acc += cv4.x * wv4.x + cv4.y * wv4.y + cv4.z * wv4.z + cv4.w * wv4.w;
    }
    part[q * 64 + e] = acc;
    __syncthreads();
    if (tid < NE)
      logits[tid] = part[tid] + part[64 + tid] + part[128 + tid] + part[192 + tid] + bias[tid];
    __syncthreads();
    if (tid == 0) {
      int i0 = 0; float l0 = logits[0];
      for (int i = 1; i < NE; ++i) { float v = logits[i]; if (v > l0) { l0 = v; i0 = i; } }
      int i1 = -1; float l1 = -3.4e38f;
      for (int i = 0; i < NE; ++i) {
        if (i == i0) continue;
        float v = logits[i]; if (v > l1) { l1 = v; i1 = i; }
      }
      float w0 = 1.f / (1.f + expf(l1 - l0));
      sel_i[0] = i0; sel_i[1] = i1;
      sel_f[0] = w0; sel_f[1] = 1.f - w0;
    }
    __syncthreads();
  }
  int e0 = sel_i[0], e1 = sel_i[1];
  float w0 = sel_f[0], w1 = sel_f[1];

  for (int i = tid; i < DIM; i += 256) cnt[i] = 0;
  __syncthreads();
  for (int k = tid; k < 2 * NFRQ; k += 256) {
    int t = k >> 11, j = k & (NFRQ - 1);
    int e = t ? e1 : e0;
    int f = lidx[e * NFRQ + j];
    atomicAdd(&cnt[f / DIM], 1);
  }
  __syncthreads();
  {  // parallel exclusive scan of cnt[768]: 3 per thread
    int s0 = cnt[3 * tid], s1 = cnt[3 * tid + 1], s2 = cnt[3 * tid + 2];
    int sum = s0 + s1 + s2;
    int lane = tid & 63, wid = tid >> 6;
    int v = sum;
#pragma unroll
    for (int d = 1; d < 64; d <<= 1) {
      int u = __shfl_up(v, d);
      if (lane >= d) v += u;
    }
    if (lane == 63) wsum[wid] = v;
    __syncthreads();
    int woff = 0;
#pragma unroll
    for (int w = 0; w < 4; ++w) if (w < wid) woff += wsum[w];
    int excl = woff + v - sum;
    int* rsg = row_start + b * (DIM + 1);
    base[3 * tid]     = excl;
    base[3 * tid + 1] = excl + s0;
    base[3 * tid + 2] = excl + s0 + s1;
    rsg[3 * tid]     = excl;
    rsg[3 * tid + 1] = excl + s0;
    rsg[3 * tid + 2] = excl + s0 + s1;
    if (tid == 255) rsg[DIM] = excl + sum;   // == 4096
  }
  __syncthreads();
  for (int i = tid; i < DIM; i += 256) cnt[i] = 0;
  __syncthreads();
  for (int k = tid; k < 2 * NFRQ; k += 256) {
    int t = k >> 11, j = k & (NFRQ - 1);
    int e = t ? e1 : e0;
    float w = t ? w1 : w0;
    int f = lidx[e * NFRQ + j];
    int r = f / DIM, c = f - r * DIM;
    int pos = base[r] + atomicAdd(&cnt[r], 1);
    s_cv[b * 4096 + pos] = make_float2(__uint_as_float((unsigned)c * 3072u),
                                       coeff[e * NFRQ + j] * w * SCALE);
  }
}

// ---------------------------------------------------------------------------
// Kernel B (v7): v6 algorithm, but the 8 T2 loads are FORCED into one
// back-to-back cluster via a single inline-asm block (8 global_load_dwordx4
// + one s_waitcnt vmcnt(0)). R16 proved the scheduler serializes them when
// left to its own devices (VGPR stuck at 48). The asm block demands 8 live
// destination quads -> true 8-way memory-level parallelism.
// ---------------------------------------------------------------------------
__global__ __launch_bounds__(512, 2) void stage1_kernel(const int* __restrict__ row_start,
                                                        const float2* __restrict__ s_cv,
                                                        const float2* __restrict__ T2,
                                                        __hip_bfloat16* __restrict__ BT) {
  int b = blockIdx.z;
  int xg = blockIdx.y;                  // 0..2 (x-chunk of 128)
  int rg = blockIdx.x;                  // 0..11 (32 pair-rows)
  int tid = threadIdx.x;                // 512
  int lane = tid & 63, w = tid >> 6;    // w in 0..7
  __shared__ __hip_bfloat16 lds[4][32][132];   // 0:ReP 1:ImP 2:ReM 3:ImM
  const int* rs = row_start + b * (DIM + 1);
  const float2* cv = s_cv + b * 4096;
  int rowBase = rg * 32;
  size_t xbyte = (size_t)xg * 1024 + (size_t)lane * 16;   // float4 per lane
  const char* T2b = (const char*)T2;

  // wave w owns pairs pbase..pbase+3; 8 streams: s -> row pbase+(s>>1)+(s&1)*384
  int pbase = rowBase + w * 4;
  int sstart[8], scount[8];
#pragma unroll
  for (int s = 0; s < 8; ++s) {
    int row = pbase + (s >> 1) + (s & 1) * 384;
    int st = rs[row];
    sstart[s] = st;
    scount[s] = rs[row + 1] - st;
  }
  int kmax = 0;
#pragma unroll
  for (int s = 0; s < 8; ++s) kmax = scount[s] > kmax ? scount[s] : kmax;

  float acc[8][4];
#pragma unroll
  for (int s = 0; s < 8; ++s) { acc[s][0] = acc[s][1] = acc[s][2] = acc[s][3] = 0.f; }

  // prologue: cv for k=0 (clamped: empty stream -> its own start, still valid)
  float2 c[8];
#pragma unroll
  for (int s = 0; s < 8; ++s) {
    int idx = sstart[s] < 4095 ? sstart[s] : 4095;
    c[s] = cv[idx];
  }

  for (int k = 0; k < kmax; ++k) {
    // 1) addresses for all 8 T2 loads (ready from previous iteration's cv)
    const char* a0 = T2b + (size_t)__float_as_uint(c[0].x) + xbyte;
    const char* a1 = T2b + (size_t)__float_as_uint(c[1].x) + xbyte;
    const char* a2 = T2b + (size_t)__float_as_uint(c[2].x) + xbyte;
    const char* a3 = T2b + (size_t)__float_as_uint(c[3].x) + xbyte;
    const char* a4 = T2b + (size_t)__float_as_uint(c[4].x) + xbyte;
    const char* a5 = T2b + (size_t)__float_as_uint(c[5].x) + xbyte;
    const char* a6 = T2b + (size_t)__float_as_uint(c[6].x) + xbyte;
    const char* a7 = T2b + (size_t)__float_as_uint(c[7].x) + xbyte;
    f32x4 t0, t1, t2, t3, t4, t5, t6, t7;
    // forced 8-load cluster: all issue before the single wait
    asm volatile(
        "global_load_dwordx4 %[t0], %[a0], off\n\t"
        "global_load_dwordx4 %[t1], %[a1], off\n\t"
        "global_load_dwordx4 %[t2], %[a2], off\n\t"
        "global_load_dwordx4 %[t3], %[a3], off\n\t"
        "global_load_dwordx4 %[t4], %[a4], off\n\t"
        "global_load_dwordx4 %[t5], %[a5], off\n\t"
        "global_load_dwordx4 %[t6], %[a6], off\n\t"
        "global_load_dwordx4 %[t7], %[a7], off\n\t"
        "s_waitcnt vmcnt(0)"
        : [t0] "=&v"(t0), [t1] "=&v"(t1), [t2] "=&v"(t2), [t3] "=&v"(t3),
          [t4] "=&v"(t4), [t5] "=&v"(t5), [t6] "=&v"(t6), [t7] "=&v"(t7)
        : [a0] "v"(a0), [a1] "v"(a1), [a2] "v"(a2), [a3] "v"(a3),
          [a4] "v"(a4), [a5] "v"(a5), [a6] "v"(a6), [a7] "v"(a7)
        : "memory");
    __builtin_amdgcn_sched_barrier(0);
    // 2) next-cv loads (independent; compiler-scheduled, L1-resident)
    float2 cn[8];
#pragma unroll
    for (int s = 0; s < 8; ++s) {
      int kk = (k + 1) < scount[s] ? (k + 1) : 0;     // cndmask, no branch
      int idx = sstart[s] + kk;
      idx = idx < 4095 ? idx : 4095;
      cn[s] = cv[idx];
    }
    // 3) FMAs (value zeroed for expired streams -> exact no-op)
#define FMA_S(i, ts)                                                    \
    {                                                                   \
      float v = k < scount[i] ? c[i].y : 0.f;                           \
      acc[i][0] += v * ts[0]; acc[i][1] += v * ts[1];                   \
      acc[i][2] += v * ts[2]; acc[i][3] += v * ts[3];                   \
    }
    FMA_S(0, t0) FMA_S(1, t1) FMA_S(2, t2) FMA_S(3, t3)
    FMA_S(4, t4) FMA_S(5, t5) FMA_S(6, t6) FMA_S(7, t7)
#undef FMA_S
#pragma unroll
    for (int s = 0; s < 8; ++s) c[s] = cn[s];
  }

  // combine P = A+B, M = A-B per pair q: A = stream 2q, B = stream 2q+1
  // t layout: x0=xg*128+2*lane (cos,-sin), x1=x0+1 -> acc[.]={re0,-im0,re1,-im1}
  int xl = 2 * lane;
  union { __hip_bfloat16 h[2]; unsigned u; } u0;
#pragma unroll
  for (int q = 0; q < 4; ++q) {
    int slot = w * 4 + q;
    const float* aa = acc[2 * q];
    const float* bb = acc[2 * q + 1];
    u0.h[0] = __float2bfloat16(aa[0] + bb[0]); u0.h[1] = __float2bfloat16(aa[2] + bb[2]);
    *(unsigned*)&lds[0][slot][xl] = u0.u;                       // ReP
    u0.h[0] = __float2bfloat16(aa[1] + bb[1]); u0.h[1] = __float2bfloat16(aa[3] + bb[3]);
    *(unsigned*)&lds[1][slot][xl] = u0.u;                       // -ImP
    u0.h[0] = __float2bfloat16(aa[0] - bb[0]); u0.h[1] = __float2bfloat16(aa[2] - bb[2]);
    *(unsigned*)&lds[2][slot][xl] = u0.u;                       // ReM
    u0.h[0] = __float2bfloat16(aa[1] - bb[1]); u0.h[1] = __float2bfloat16(aa[3] - bb[3]);
    *(unsigned*)&lds[3][slot][xl] = u0.u;                       // -ImM
  }
  __syncthreads();
  // flush: 4 arrays x 128 x = 512 tasks = 1/thread; each one FULL 64B line
  {
    int a = tid >> 7, x = tid & 127;
    union { ushort h[32]; uint4 v[4]; } u;
#pragma unroll
    for (int k = 0; k < 32; ++k) u.h[k] = *(const ushort*)&lds[a][k][x];
    __hip_bfloat16* dst = BT + ((size_t)(b * HALF + xg * 128 + x)) * KROW + a * HALF + rowBase;
#pragma unroll
    for (int q = 0; q < 4; ++q) *(uint4*)(dst + q * 8) = u.v[q];
  }
}

// ---------------------------------------------------------------------------
// Kernel C: nyq blocks (bid<128) + parity quadrant GEMM  [unchanged]
// BK=64, 12 steps, double-buffer + __syncthreads, 8-slot XOR swizzle.
// ---------------------------------------------------------------------------
__device__ inline void gload_lds16(const void* g, void* l) {
  __builtin_amdgcn_global_load_lds((const __attribute__((address_space(1))) void*)g,
                                   (__attribute__((address_space(3))) void*)l, 16, 0, 0);
}

__global__ __launch_bounds__(256) void gemm_kernel(const __hip_bfloat16* __restrict__ A,
                                                   const __hip_bfloat16* __restrict__ BT,
                                                   const int* __restrict__ row_start,
                                                   const float2* __restrict__ s_cv,
                                                   float* __restrict__ C) {
  int bid = blockIdx.x;
  int tid = threadIdx.x;
  __shared__ __align__(16) __hip_bfloat16 As[2][64 * 64];   // 16KB
  __shared__ __align__(16) __hip_bfloat16 Bs[2][64 * 64];   // 16KB

  if (bid < 4 * NB) {                 // ---- Nyquist blocks ----
    int slice = bid & 3, b = bid >> 2;
    float* ob = C + (size_t)b * DIM * DIM;
    if (slice == 3) {                 // row y=384: sum_rp (-1)^rp ReP[rp,x]
      for (int x = tid; x < HALF; x += 256) {
        const __hip_bfloat16* btx = BT + ((size_t)(b * HALF + x)) * KROW;
        float acc = 0.f;
        for (int r = 0; r < HALF; r += 8) {
          union { uint4 v4; __hip_bfloat16 h[8]; } u;
          u.v4 = *(const uint4*)(btx + r);
#pragma unroll
          for (int q = 0; q < 8; ++q) {
            float v = __bfloat162float(u.h[q]);
            acc += (q & 1) ? -v : v;
          }
        }
        int xm = x ? DIM - x : 0;
        ob[(size_t)HALF * DIM + x]  = acc;
        ob[(size_t)HALF * DIM + xm] = acc;
      }
      return;
    }
    // slices 0..2: column x=384
    float* Re384 = (float*)As;        // reuse LDS
    const int* rs = row_start + b * (DIM + 1);
    const float2* cv = s_cv + b * 4096;
    for (int r = tid; r < DIM; r += 256) {
      int s = rs[r], e = rs[r + 1];
      float acc = 0.f;
      for (int p = s; p < e; ++p) {
        float2 c = cv[p];
        int ci = (int)(__float_as_uint(c.x) / 3072u);
        acc += (ci & 1) ? -c.y : c.y;
      }
      Re384[r] = acc;
    }
    __syncthreads();
    int y = slice * 129 + tid;
    if (tid < 129 && y <= HALF) {
      float yf = (float)y;
      float a0 = 0.f, a1 = 0.f, a2 = 0.f, a3 = 0.f;
      for (int r = 0; r < DIM; r += 4) {
        float f0, f1, f2, f3, c0, c1, c2, c3;
        float v0 = (yf * (float)(r + 0)) * INV768;
        float v1 = (yf * (float)(r + 1)) * INV768;
        float v2 = (yf * (float)(r + 2)) * INV768;
        float v3 = (yf * (float)(r + 3)) * INV768;
        asm("v_fract_f32 %0, %1" : "=v"(f0) : "v"(v0));
        asm("v_fract_f32 %0, %1" : "=v"(f1) : "v"(v1));
        asm("v_fract_f32 %0, %1" : "=v"(f2) : "v"(v2));
        asm("v_fract_f32 %0, %1" : "=v"(f3) : "v"(v3));
        asm("v_cos_f32 %0, %1" : "=v"(c0) : "v"(f0));
        asm("v_cos_f32 %0, %1" : "=v"(c1) : "v"(f1));
        asm("v_cos_f32 %0, %1" : "=v"(c2) : "v"(f2));
        asm("v_cos_f32 %0, %1" : "=v"(c3) : "v"(f3));
        a0 += Re384[r + 0] * c0;
        a1 += Re384[r + 1] * c1;
        a2 += Re384[r + 2] * c2;
        a3 += Re384[r + 3] * c3;
      }
      float acc = (a0 + a1) + (a2 + a3);
      int ym = y ? DIM - y : 0;
      ob[(size_t)y  * DIM + HALF] = acc;
      ob[(size_t)ym * DIM + HALF] = acc;
    }
    return;
  }

  // ---- GEMM blocks: 1152 = 8*144; 36 tiles/batch = 2 par x 6 bx x 3 by ----
  int gbid = bid - 4 * NB;
  int swz = (gbid & 7) * 144 + (gbid >> 3);
  int b = swz / 36; int rem = swz - b * 36;
  int par = rem / 18; int r2 = rem - par * 18;
  int bx = r2 / 3, by = r2 % 3;

  float* Cp = C + (size_t)b * DIM * DIM;
  int y0 = by * 64, x0 = bx * 64;     // y0 in t-space [0,192)

  int wv = tid >> 6, lane = tid & 63;
  int wr = wv >> 1, wc = wv & 1;      // wave: 32x32 sub-tile
  int lhi = lane >> 4, llo = lane & 15;

  int c0 = tid, c1 = tid + 256;
  int row0 = c0 >> 3, row1 = c1 >> 3;
  int so0 = (((c0 & 7) ^ (row0 & 7))) * 8;
  int so1 = (((c1 & 7) ^ (row1 & 7))) * 8;

  f32x4 acc1[2][2] = {};
  f32x4 acc2[2][2] = {};

  const __hip_bfloat16* A0 = A  + ((size_t)(par * 192 + y0 + row0)) * KG + so0;
  const __hip_bfloat16* A1 = A  + ((size_t)(par * 192 + y0 + row1)) * KG + so1;
  const __hip_bfloat16* B0 = BT + ((size_t)(b * HALF + x0 + row0)) * KROW + par * KG + so0;
  const __hip_bfloat16* B1 = BT + ((size_t)(b * HALF + x0 + row1)) * KROW + par * KG + so1;

  gload_lds16(A0, As[0] + c0 * 8);
  gload_lds16(A1, As[0] + c1 * 8);
  gload_lds16(B0, Bs[0] + c0 * 8);
  gload_lds16(B1, Bs[0] + c1 * 8);
  __syncthreads();

  auto step = [&](int t, f32x4 (&acc)[2][2], bool last) {
    int cur = t & 1;
    if (!last) {
      int ktn = (t + 1) * 64;
      gload_lds16(A0 + ktn, As[cur ^ 1] + c0 * 8);
      gload_lds16(A1 + ktn, As[cur ^ 1] + c1 * 8);
      gload_lds16(B0 + ktn, Bs[cur ^ 1] + c0 * 8);
      gload_lds16(B1 + ktn, Bs[cur ^ 1] + c1 * 8);
    }
    bf16x8 af[2][2], bfr[2][2];
#pragma unroll
    for (int i = 0; i < 2; ++i)
#pragma unroll
      for (int kh = 0; kh < 2; ++kh) {
        int row = wr * 32 + i * 16 + llo;
        int phys = ((lhi + 4 * kh) ^ (llo & 7)) * 8;
        af[i][kh] = *(const bf16x8*)(As[cur] + row * 64 + phys);
      }
#pragma unroll
    for (int j = 0; j < 2; ++j)
#pragma unroll
      for (int kh = 0; kh < 2; ++kh) {
        int row = wc * 32 + j * 16 + llo;
        int phys = ((lhi + 4 * kh) ^ (llo & 7)) * 8;
        bfr[j][kh] = *(const bf16x8*)(Bs[cur] + row * 64 + phys);
      }
#pragma unroll
    for (int kh = 0; kh < 2; ++kh)
#pragma unroll
      for (int i = 0; i < 2; ++i)
#pragma unroll
        for (int j = 0; j < 2; ++j)
          acc[i][j] = __builtin_amdgcn_mfma_f32_16x16x32_bf16(af[i][kh], bfr[j][kh],
                                                              acc[i][j], 0, 0, 0);
    if (!last) __syncthreads();
  };

  for (int t = 0; t < 6; ++t)  step(t, acc1, false);       // cos half
  for (int t = 6; t < 12; ++t) step(t, acc2, t == 11);     // sin half

#pragma unroll
  for (int i = 0; i < 2; ++i) {
#pragma unroll
    for (int j = 0; j < 2; ++j) {
      int x = x0 + wc * 32 + j * 16 + llo;
      int xm = x ? DIM - x : 0;
#pragma unroll
      for (int q = 0; q < 4; ++q) {
        int tt = y0 + wr * 32 + i * 16 + lhi * 4 + q;
        int y = 2 * tt + par;
        int ym = y ? DIM - y : 0;
        float c1 = acc1[i][j][q], c2 = acc2[i][j][q];
        float vd = c1 + c2;
        float vs = c1 - c2;
        Cp[(size_t)y  * DIM + x]  = vd;
        Cp[(size_t)ym * DIM + xm] = vd;
        Cp[(size_t)y  * DIM + xm] = vs;
        Cp[(size_t)ym * DIM + x]  = vs;
      }
    }
  }
}

// ---------------------------------------------------------------------------
extern "C" void kernel_launch(void* const* d_in, const int* in_sizes, int n_in,
                              void* d_out, int out_size, void* d_ws, size_t ws_size,
                              hipStream_t stream) {
  const float* cls   = (const float*)d_in[0];
  const float* Wr    = (const float*)d_in[1];
  const float* br    = (const float*)d_in[2];
  const float* coeff = (const float*)d_in[3];
  const int*   lidx  = (const int*)d_in[4];
  float* out = (float*)d_out;

  char* ws = (char*)d_ws;
  int*    row_start = (int*)(ws + 0);           //    98,432
  float2* s_cv      = (float2*)(ws + 98944);    // 1,048,576 (ends 1,147,520)
  __hip_bfloat16* A  = (__hip_bfloat16*)(ws + 1147520);  // 589,824 (ends 1,737,344)
  float2* T2        = (float2*)(ws + 1737344);  // 2,359,296 (ends 4,096,640)
  __hip_bfloat16* BT = (__hip_bfloat16*)(ws + 4096640);  // 37,748,736 (~42 MB)

  prep_kernel<<<32 + 384 + DIM, 256, 0, stream>>>(cls, Wr, br, coeff, lidx,
                                                  row_start, s_cv, A, T2);
  stage1_kernel<<<dim3(12, 3, NB), 512, 0, stream>>>(row_start, s_cv, T2, BT);
  gemm_kernel<<<4 * NB + 1152, 256, 0, stream>>>(A, BT, row_start, s_cv, out);
}

// Round 18
// 111.418 us; speedup vs baseline: 1.1445x; 1.1445x over previous
//
#include <hip/hip_runtime.h>
#include <hip/hip_bf16.h>

#define DIM 768
#define NE 64
#define NFRQ 2048
#define NB 32
#define HALF 384                // computed quadrant extent (y,x in [0,384))
#define KROW 1536               // BT per-x row elems: [ReP|-ImP|ReM|-ImM] x 384
#define KG 768                  // GEMM K per parity (384 cos + 384 sin)
#define TWO_PI 6.283185307179586f
#define INV768 (1.0f / 768.0f)
#define SCALE (300.0f / (float)(DIM * DIM))   // ALPHA / (dim*dim), folded into values

typedef __attribute__((ext_vector_type(8))) short bf16x8;   // 8 bf16 (4 VGPRs)
typedef __attribute__((ext_vector_type(4))) float f32x4;    // MFMA accumulator

// ---------------------------------------------------------------------------
// Kernel A "prep" (one launch, 2 roles by blockIdx):
//  bid < 32   : fused router + bucket-sort build; s_cv = (colf, weighted val)
//  bid >= 32  : A twiddle row idx = bid-32 (parity layout)
// ---------------------------------------------------------------------------
__global__ __launch_bounds__(256) void prep_kernel(const float* __restrict__ cls,
                                                   const float* __restrict__ W,
                                                   const float* __restrict__ bias,
                                                   const float* __restrict__ coeff,
                                                   const int* __restrict__ lidx,
                                                   int* __restrict__ row_start,
                                                   float2* __restrict__ s_cv,
                                                   __hip_bfloat16* __restrict__ A) {
  int bid = blockIdx.x;
  int tid = threadIdx.x;

  if (bid >= 32) {                    // ---- A twiddle rows (parity layout) ----
    int idx = bid - 32;               // 0..383 ; row idx = par*192 + t
    int y = 2 * (idx % 192) + (idx / 192);
    if (tid < 96) {
      int r0 = tid * 4;
      union { __hip_bfloat16 h[4]; ushort4 v; } uc, us;
#pragma unroll
      for (int j = 0; j < 4; ++j) {
        int m = (y * (r0 + j)) % DIM;
        float s, c;
        sincosf((TWO_PI / (float)DIM) * (float)m, &s, &c);
        uc.h[j] = __float2bfloat16(c);
        us.h[j] = __float2bfloat16(s);
      }
      *(ushort4*)(A + (size_t)idx * KG + r0)        = uc.v;
      *(ushort4*)(A + (size_t)idx * KG + HALF + r0) = us.v;
    }
    return;
  }

  // ---- router + build, batch b = bid ----
  int b = bid;
  __shared__ int cnt[DIM];
  __shared__ int base[DIM];
  __shared__ int wsum[4];
  __shared__ int sel_i[2];
  __shared__ float sel_f[2];
  float* part   = (float*)cnt;
  float* logits = (float*)base;

  {
    int e = tid & 63, q = tid >> 6;
    const float* c = cls + b * DIM + q * 192;
    const float* w = W + e * DIM + q * 192;
    float acc = 0.f;
#pragma unroll 4
    for (int i = 0; i < 192; i += 4) {
      float4 cv4 = *(const float4*)(c + i);
      float4 wv4 = *(const float4*)(w + i);
      acc += cv4.x * wv4.x + cv4.y * wv4.y + cv4.z * wv4.z + cv4.w * wv4.w;
    }
    part[q * 64 + e] = acc;
    __syncthreads();
    if (tid < NE)
      logits[tid] = part[tid] + part[64 + tid] + part[128 + tid] + part[192 + tid] + bias[tid];
    __syncthreads();
    if (tid == 0) {
      int i0 = 0; float l0 = logits[0];
      for (int i = 1; i < NE; ++i) { float v = logits[i]; if (v > l0) { l0 = v; i0 = i; } }
      int i1 = -1; float l1 = -3.4e38f;
      for (int i = 0; i < NE; ++i) {
        if (i == i0) continue;
        float v = logits[i]; if (v > l1) { l1 = v; i1 = i; }
      }
      float w0 = 1.f / (1.f + expf(l1 - l0));
      sel_i[0] = i0; sel_i[1] = i1;
      sel_f[0] = w0; sel_f[1] = 1.f - w0;
    }
    __syncthreads();
  }
  int e0 = sel_i[0], e1 = sel_i[1];
  float w0 = sel_f[0], w1 = sel_f[1];

  for (int i = tid; i < DIM; i += 256) cnt[i] = 0;
  __syncthreads();
  for (int k = tid; k < 2 * NFRQ; k += 256) {
    int t = k >> 11, j = k & (NFRQ - 1);
    int e = t ? e1 : e0;
    int f = lidx[e * NFRQ + j];
    atomicAdd(&cnt[f / DIM], 1);
  }
  __syncthreads();
  {  // parallel exclusive scan of cnt[768]: 3 per thread
    int s0 = cnt[3 * tid], s1 = cnt[3 * tid + 1], s2 = cnt[3 * tid + 2];
    int sum = s0 + s1 + s2;
    int lane = tid & 63, wid = tid >> 6;
    int v = sum;
#pragma unroll
    for (int d = 1; d < 64; d <<= 1) {
      int u = __shfl_up(v, d);
      if (lane >= d) v += u;
    }
    if (lane == 63) wsum[wid] = v;
    __syncthreads();
    int woff = 0;
#pragma unroll
    for (int w = 0; w < 4; ++w) if (w < wid) woff += wsum[w];
    int excl = woff + v - sum;
    int* rsg = row_start + b * (DIM + 1);
    base[3 * tid]     = excl;
    base[3 * tid + 1] = excl + s0;
    base[3 * tid + 2] = excl + s0 + s1;
    rsg[3 * tid]     = excl;
    rsg[3 * tid + 1] = excl + s0;
    rsg[3 * tid + 2] = excl + s0 + s1;
    if (tid == 255) rsg[DIM] = excl + sum;   // == 4096
  }
  __syncthreads();
  for (int i = tid; i < DIM; i += 256) cnt[i] = 0;
  __syncthreads();
  for (int k = tid; k < 2 * NFRQ; k += 256) {
    int t = k >> 11, j = k & (NFRQ - 1);
    int e = t ? e1 : e0;
    float w = t ? w1 : w0;
    int f = lidx[e * NFRQ + j];
    int r = f / DIM, c = f - r * DIM;
    int pos = base[r] + atomicAdd(&cnt[r], 1);
    s_cv[b * 4096 + pos] = make_float2((float)c,
                                       coeff[e * NFRQ + j] * w * SCALE);
  }
}

// ---------------------------------------------------------------------------
// Kernel B (v8): stage-1, 8 waves x 8 streams, but trig computed IN-REGISTER
// (v_fract/v_sin/v_cos) instead of reading the T2 table. R12-R17 showed every
// load-based variant pinned at 56-88us by the L1 random-row miss path; direct
// trig removes all random loads (only wave-uniform 8B cv broadcasts remain)
// -> trans/VALU throughput bound. Values bitwise-identical to the T2 table
// (same instructions generated it).
// ---------------------------------------------------------------------------
__global__ __launch_bounds__(512, 2) void stage1_kernel(const int* __restrict__ row_start,
                                                        const float2* __restrict__ s_cv,
                                                        __hip_bfloat16* __restrict__ BT) {
  int b = blockIdx.z;
  int xg = blockIdx.y;                  // 0..2 (x-chunk of 128)
  int rg = blockIdx.x;                  // 0..11 (32 pair-rows)
  int tid = threadIdx.x;                // 512
  int lane = tid & 63, w = tid >> 6;    // w in 0..7
  __shared__ __hip_bfloat16 lds[4][32][132];   // 0:ReP 1:ImP 2:ReM 3:ImM
  const int* rs = row_start + b * (DIM + 1);
  const float2* cv = s_cv + b * 4096;
  int rowBase = rg * 32;
  float xf0 = (float)(xg * 128 + 2 * lane);   // this lane's two x values
  float xf1 = xf0 + 1.0f;

  // wave w owns pairs pbase..pbase+3; 8 streams: s -> row pbase+(s>>1)+(s&1)*384
  int pbase = rowBase + w * 4;
  int sstart[8], scount[8];
#pragma unroll
  for (int s = 0; s < 8; ++s) {
    int row = pbase + (s >> 1) + (s & 1) * 384;
    int st = rs[row];
    sstart[s] = st;
    scount[s] = rs[row + 1] - st;
  }
  int kmax = 0;
#pragma unroll
  for (int s = 0; s < 8; ++s) kmax = scount[s] > kmax ? scount[s] : kmax;

  float acc[8][4];    // {re0, im0, re1, im1}; im = +sum(v*sin), negated at pack
#pragma unroll
  for (int s = 0; s < 8; ++s) { acc[s][0] = acc[s][1] = acc[s][2] = acc[s][3] = 0.f; }

  // prologue: cv for k=0 (clamped: empty stream -> its own start, still valid)
  float2 c[8];
#pragma unroll
  for (int s = 0; s < 8; ++s) {
    int idx = sstart[s] < 4095 ? sstart[s] : 4095;
    c[s] = cv[idx];
  }

  for (int k = 0; k < kmax; ++k) {
    // 1) next-cv loads first (latency hides under the trig below)
    float2 cn[8];
#pragma unroll
    for (int s = 0; s < 8; ++s) {
      int kk = (k + 1) < scount[s] ? (k + 1) : 0;     // cndmask, no branch
      int idx = sstart[s] + kk;
      idx = idx < 4095 ? idx : 4095;
      cn[s] = cv[idx];
    }
    // 2) trig + FMA per stream (branchless; expired streams add exact zeros)
#pragma unroll
    for (int s = 0; s < 8; ++s) {
      float v = k < scount[s] ? c[s].y : 0.f;         // cndmask, no branch
      float colf = c[s].x;
      float r0 = (colf * xf0) * INV768;               // integer product < 2^24, exact
      float r1 = (colf * xf1) * INV768;
      float f0, f1, sn0, sn1, cs0, cs1;
      asm("v_fract_f32 %0, %1" : "=v"(f0) : "v"(r0));
      asm("v_fract_f32 %0, %1" : "=v"(f1) : "v"(r1));
      asm("v_sin_f32 %0, %1" : "=v"(sn0) : "v"(f0));
      asm("v_cos_f32 %0, %1" : "=v"(cs0) : "v"(f0));
      asm("v_sin_f32 %0, %1" : "=v"(sn1) : "v"(f1));
      asm("v_cos_f32 %0, %1" : "=v"(cs1) : "v"(f1));
      acc[s][0] += v * cs0; acc[s][1] += v * sn0;
      acc[s][2] += v * cs1; acc[s][3] += v * sn1;
    }
#pragma unroll
    for (int s = 0; s < 8; ++s) c[s] = cn[s];
  }

  // combine P = A+B, M = A-B per pair q: A = stream 2q, B = stream 2q+1
  // stored layout per x: Re..., then -Im (minus sign applied here)
  int xl = 2 * lane;
  union { __hip_bfloat16 h[2]; unsigned u; } u0;
#pragma unroll
  for (int q = 0; q < 4; ++q) {
    int slot = w * 4 + q;
    const float* aa = acc[2 * q];
    const float* bb = acc[2 * q + 1];
    u0.h[0] = __float2bfloat16(aa[0] + bb[0]); u0.h[1] = __float2bfloat16(aa[2] + bb[2]);
    *(unsigned*)&lds[0][slot][xl] = u0.u;                       // ReP
    u0.h[0] = __float2bfloat16(-(aa[1] + bb[1])); u0.h[1] = __float2bfloat16(-(aa[3] + bb[3]));
    *(unsigned*)&lds[1][slot][xl] = u0.u;                       // -ImP
    u0.h[0] = __float2bfloat16(aa[0] - bb[0]); u0.h[1] = __float2bfloat16(aa[2] - bb[2]);
    *(unsigned*)&lds[2][slot][xl] = u0.u;                       // ReM
    u0.h[0] = __float2bfloat16(-(aa[1] - bb[1])); u0.h[1] = __float2bfloat16(-(aa[3] - bb[3]));
    *(unsigned*)&lds[3][slot][xl] = u0.u;                       // -ImM
  }
  __syncthreads();
  // flush: 4 arrays x 128 x = 512 tasks = 1/thread; each one FULL 64B line
  {
    int a = tid >> 7, x = tid & 127;
    union { ushort h[32]; uint4 v[4]; } u;
#pragma unroll
    for (int k = 0; k < 32; ++k) u.h[k] = *(const ushort*)&lds[a][k][x];
    __hip_bfloat16* dst = BT + ((size_t)(b * HALF + xg * 128 + x)) * KROW + a * HALF + rowBase;
#pragma unroll
    for (int q = 0; q < 4; ++q) *(uint4*)(dst + q * 8) = u.v[q];
  }
}

// ---------------------------------------------------------------------------
// Kernel C: nyq blocks (bid<128) + parity quadrant GEMM  [unchanged except
// nyq parity read uses colf format]. BK=64, 12 steps, dbuf + __syncthreads,
// 8-slot XOR swizzle.
// ---------------------------------------------------------------------------
__device__ inline void gload_lds16(const void* g, void* l) {
  __builtin_amdgcn_global_load_lds((const __attribute__((address_space(1))) void*)g,
                                   (__attribute__((address_space(3))) void*)l, 16, 0, 0);
}

__global__ __launch_bounds__(256) void gemm_kernel(const __hip_bfloat16* __restrict__ A,
                                                   const __hip_bfloat16* __restrict__ BT,
                                                   const int* __restrict__ row_start,
                                                   const float2* __restrict__ s_cv,
                                                   float* __restrict__ C) {
  int bid = blockIdx.x;
  int tid = threadIdx.x;
  __shared__ __align__(16) __hip_bfloat16 As[2][64 * 64];   // 16KB
  __shared__ __align__(16) __hip_bfloat16 Bs[2][64 * 64];   // 16KB

  if (bid < 4 * NB) {                 // ---- Nyquist blocks ----
    int slice = bid & 3, b = bid >> 2;
    float* ob = C + (size_t)b * DIM * DIM;
    if (slice == 3) {                 // row y=384: sum_rp (-1)^rp ReP[rp,x]
      for (int x = tid; x < HALF; x += 256) {
        const __hip_bfloat16* btx = BT + ((size_t)(b * HALF + x)) * KROW;
        float acc = 0.f;
        for (int r = 0; r < HALF; r += 8) {
          union { uint4 v4; __hip_bfloat16 h[8]; } u;
          u.v4 = *(const uint4*)(btx + r);
#pragma unroll
          for (int q = 0; q < 8; ++q) {
            float v = __bfloat162float(u.h[q]);
            acc += (q & 1) ? -v : v;
          }
        }
        int xm = x ? DIM - x : 0;
        ob[(size_t)HALF * DIM + x]  = acc;
        ob[(size_t)HALF * DIM + xm] = acc;
      }
      return;
    }
    // slices 0..2: column x=384
    float* Re384 = (float*)As;        // reuse LDS
    const int* rs = row_start + b * (DIM + 1);
    const float2* cv = s_cv + b * 4096;
    for (int r = tid; r < DIM; r += 256) {
      int s = rs[r], e = rs[r + 1];
      float acc = 0.f;
      for (int p = s; p < e; ++p) {
        float2 c = cv[p];
        int ci = (int)c.x;
        acc += (ci & 1) ? -c.y : c.y;
      }
      Re384[r] = acc;
    }
    __syncthreads();
    int y = slice * 129 + tid;
    if (tid < 129 && y <= HALF) {
      float yf = (float)y;
      float a0 = 0.f, a1 = 0.f, a2 = 0.f, a3 = 0.f;
      for (int r = 0; r < DIM; r += 4) {
        float f0, f1, f2, f3, c0, c1, c2, c3;
        float v0 = (yf * (float)(r + 0)) * INV768;
        float v1 = (yf * (float)(r + 1)) * INV768;
        float v2 = (yf * (float)(r + 2)) * INV768;
        float v3 = (yf * (float)(r + 3)) * INV768;
        asm("v_fract_f32 %0, %1" : "=v"(f0) : "v"(v0));
        asm("v_fract_f32 %0, %1" : "=v"(f1) : "v"(v1));
        asm("v_fract_f32 %0, %1" : "=v"(f2) : "v"(v2));
        asm("v_fract_f32 %0, %1" : "=v"(f3) : "v"(v3));
        asm("v_cos_f32 %0, %1" : "=v"(c0) : "v"(f0));
        asm("v_cos_f32 %0, %1" : "=v"(c1) : "v"(f1));
        asm("v_cos_f32 %0, %1" : "=v"(c2) : "v"(f2));
        asm("v_cos_f32 %0, %1" : "=v"(c3) : "v"(f3));
        a0 += Re384[r + 0] * c0;
        a1 += Re384[r + 1] * c1;
        a2 += Re384[r + 2] * c2;
        a3 += Re384[r + 3] * c3;
      }
      float acc = (a0 + a1) + (a2 + a3);
      int ym = y ? DIM - y : 0;
      ob[(size_t)y  * DIM + HALF] = acc;
      ob[(size_t)ym * DIM + HALF] = acc;
    }
    return;
  }

  // ---- GEMM blocks: 1152 = 8*144; 36 tiles/batch = 2 par x 6 bx x 3 by ----
  int gbid = bid - 4 * NB;
  int swz = (gbid & 7) * 144 + (gbid >> 3);
  int b = swz / 36; int rem = swz - b * 36;
  int par = rem / 18; int r2 = rem - par * 18;
  int bx = r2 / 3, by = r2 % 3;

  float* Cp = C + (size_t)b * DIM * DIM;
  int y0 = by * 64, x0 = bx * 64;     // y0 in t-space [0,192)

  int wv = tid >> 6, lane = tid & 63;
  int wr = wv >> 1, wc = wv & 1;      // wave: 32x32 sub-tile
  int lhi = lane >> 4, llo = lane & 15;

  int c0 = tid, c1 = tid + 256;
  int row0 = c0 >> 3, row1 = c1 >> 3;
  int so0 = (((c0 & 7) ^ (row0 & 7))) * 8;
  int so1 = (((c1 & 7) ^ (row1 & 7))) * 8;

  f32x4 acc1[2][2] = {};
  f32x4 acc2[2][2] = {};

  const __hip_bfloat16* A0 = A  + ((size_t)(par * 192 + y0 + row0)) * KG + so0;
  const __hip_bfloat16* A1 = A  + ((size_t)(par * 192 + y0 + row1)) * KG + so1;
  const __hip_bfloat16* B0 = BT + ((size_t)(b * HALF + x0 + row0)) * KROW + par * KG + so0;
  const __hip_bfloat16* B1 = BT + ((size_t)(b * HALF + x0 + row1)) * KROW + par * KG + so1;

  gload_lds16(A0, As[0] + c0 * 8);
  gload_lds16(A1, As[0] + c1 * 8);
  gload_lds16(B0, Bs[0] + c0 * 8);
  gload_lds16(B1, Bs[0] + c1 * 8);
  __syncthreads();

  auto step = [&](int t, f32x4 (&acc)[2][2], bool last) {
    int cur = t & 1;
    if (!last) {
      int ktn = (t + 1) * 64;
      gload_lds16(A0 + ktn, As[cur ^ 1] + c0 * 8);
      gload_lds16(A1 + ktn, As[cur ^ 1] + c1 * 8);
      gload_lds16(B0 + ktn, Bs[cur ^ 1] + c0 * 8);
      gload_lds16(B1 + ktn, Bs[cur ^ 1] + c1 * 8);
    }
    bf16x8 af[2][2], bfr[2][2];
#pragma unroll
    for (int i = 0; i < 2; ++i)
#pragma unroll
      for (int kh = 0; kh < 2; ++kh) {
        int row = wr * 32 + i * 16 + llo;
        int phys = ((lhi + 4 * kh) ^ (llo & 7)) * 8;
        af[i][kh] = *(const bf16x8*)(As[cur] + row * 64 + phys);
      }
#pragma unroll
    for (int j = 0; j < 2; ++j)
#pragma unroll
      for (int kh = 0; kh < 2; ++kh) {
        int row = wc * 32 + j * 16 + llo;
        int phys = ((lhi + 4 * kh) ^ (llo & 7)) * 8;
        bfr[j][kh] = *(const bf16x8*)(Bs[cur] + row * 64 + phys);
      }
#pragma unroll
    for (int kh = 0; kh < 2; ++kh)
#pragma unroll
      for (int i = 0; i < 2; ++i)
#pragma unroll
        for (int j = 0; j < 2; ++j)
          acc[i][j] = __builtin_amdgcn_mfma_f32_16x16x32_bf16(af[i][kh], bfr[j][kh],
                                                              acc[i][j], 0, 0, 0);
    if (!last) __syncthreads();
  };

  for (int t = 0; t < 6; ++t)  step(t, acc1, false);       // cos half
  for (int t = 6; t < 12; ++t) step(t, acc2, t == 11);     // sin half

#pragma unroll
  for (int i = 0; i < 2; ++i) {
#pragma unroll
    for (int j = 0; j < 2; ++j) {
      int x = x0 + wc * 32 + j * 16 + llo;
      int xm = x ? DIM - x : 0;
#pragma unroll
      for (int q = 0; q < 4; ++q) {
        int tt = y0 + wr * 32 + i * 16 + lhi * 4 + q;
        int y = 2 * tt + par;
        int ym = y ? DIM - y : 0;
        float c1 = acc1[i][j][q], c2 = acc2[i][j][q];
        float vd = c1 + c2;
        float vs = c1 - c2;
        Cp[(size_t)y  * DIM + x]  = vd;
        Cp[(size_t)ym * DIM + xm] = vd;
        Cp[(size_t)y  * DIM + xm] = vs;
        Cp[(size_t)ym * DIM + x]  = vs;
      }
    }
  }
}

// ---------------------------------------------------------------------------
extern "C" void kernel_launch(void* const* d_in, const int* in_sizes, int n_in,
                              void* d_out, int out_size, void* d_ws, size_t ws_size,
                              hipStream_t stream) {
  const float* cls   = (const float*)d_in[0];
  const float* Wr    = (const float*)d_in[1];
  const float* br    = (const float*)d_in[2];
  const float* coeff = (const float*)d_in[3];
  const int*   lidx  = (const int*)d_in[4];
  float* out = (float*)d_out;

  char* ws = (char*)d_ws;
  int*    row_start = (int*)(ws + 0);           //    98,432
  float2* s_cv      = (float2*)(ws + 98944);    // 1,048,576 (ends 1,147,520)
  __hip_bfloat16* A  = (__hip_bfloat16*)(ws + 1147520);  // 589,824 (ends 1,737,344)
  __hip_bfloat16* BT = (__hip_bfloat16*)(ws + 1737344);  // 37,748,736 (~39.5 MB)

  prep_kernel<<<32 + 384, 256, 0, stream>>>(cls, Wr, br, coeff, lidx,
                                            row_start, s_cv, A);
  stage1_kernel<<<dim3(12, 3, NB), 512, 0, stream>>>(row_start, s_cv, BT);
  gemm_kernel<<<4 * NB + 1152, 256, 0, stream>>>(A, BT, row_start, s_cv, out);
}

// Round 19
// 106.199 us; speedup vs baseline: 1.2007x; 1.0491x over previous
//
#include <hip/hip_runtime.h>
#include <hip/hip_bf16.h>

#define DIM 768
#define NE 64
#define NFRQ 2048
#define NB 32
#define HALF 384                // computed quadrant extent (y,x in [0,384))
#define KROW 1536               // BT per-x row elems: [ReP|-ImP|ReM|-ImM] x 384
#define KG 768                  // GEMM K per parity (384 cos + 384 sin)
#define TWO_PI 6.283185307179586f
#define INV768 (1.0f / 768.0f)
#define SCALE (300.0f / (float)(DIM * DIM))   // ALPHA / (dim*dim), folded into values

typedef __attribute__((ext_vector_type(8))) short bf16x8;   // 8 bf16 (4 VGPRs)
typedef __attribute__((ext_vector_type(4))) float f32x4;    // MFMA accumulator

// ---------------------------------------------------------------------------
// Kernel A "prep" (one launch, 2 roles by blockIdx):
//  bid < 32   : fused router + bucket-sort build;
//               s_cv = float4(colf, weighted val, cos(2pi*64c/768), sin(...))
//  bid >= 32  : A twiddle row idx = bid-32 (parity layout)
// ---------------------------------------------------------------------------
__global__ __launch_bounds__(256) void prep_kernel(const float* __restrict__ cls,
                                                   const float* __restrict__ W,
                                                   const float* __restrict__ bias,
                                                   const float* __restrict__ coeff,
                                                   const int* __restrict__ lidx,
                                                   int* __restrict__ row_start,
                                                   float4* __restrict__ s_cv,
                                                   __hip_bfloat16* __restrict__ A) {
  int bid = blockIdx.x;
  int tid = threadIdx.x;

  if (bid >= 32) {                    // ---- A twiddle rows (parity layout) ----
    int idx = bid - 32;               // 0..383 ; row idx = par*192 + t
    int y = 2 * (idx % 192) + (idx / 192);
    if (tid < 96) {
      int r0 = tid * 4;
      union { __hip_bfloat16 h[4]; ushort4 v; } uc, us;
#pragma unroll
      for (int j = 0; j < 4; ++j) {
        int m = (y * (r0 + j)) % DIM;
        float s, c;
        sincosf((TWO_PI / (float)DIM) * (float)m, &s, &c);
        uc.h[j] = __float2bfloat16(c);
        us.h[j] = __float2bfloat16(s);
      }
      *(ushort4*)(A + (size_t)idx * KG + r0)        = uc.v;
      *(ushort4*)(A + (size_t)idx * KG + HALF + r0) = us.v;
    }
    return;
  }

  // ---- router + build, batch b = bid ----
  int b = bid;
  __shared__ int cnt[DIM];
  __shared__ int base[DIM];
  __shared__ int wsum[4];
  __shared__ int sel_i[2];
  __shared__ float sel_f[2];
  float* part   = (float*)cnt;
  float* logits = (float*)base;

  {
    int e = tid & 63, q = tid >> 6;
    const float* c = cls + b * DIM + q * 192;
    const float* w = W + e * DIM + q * 192;
    float acc = 0.f;
#pragma unroll 4
    for (int i = 0; i < 192; i += 4) {
      float4 cv4 = *(const float4*)(c + i);
      float4 wv4 = *(const float4*)(w + i);
      acc += cv4.x * wv4.x + cv4.y * wv4.y + cv4.z * wv4.z + cv4.w * wv4.w;
    }
    part[q * 64 + e] = acc;
    __syncthreads();
    if (tid < NE)
      logits[tid] = part[tid] + part[64 + tid] + part[128 + tid] + part[192 + tid] + bias[tid];
    __syncthreads();
    if (tid == 0) {
      int i0 = 0; float l0 = logits[0];
      for (int i = 1; i < NE; ++i) { float v = logits[i]; if (v > l0) { l0 = v; i0 = i; } }
      int i1 = -1; float l1 = -3.4e38f;
      for (int i = 0; i < NE; ++i) {
        if (i == i0) continue;
        float v = logits[i]; if (v > l1) { l1 = v; i1 = i; }
      }
      float w0 = 1.f / (1.f + expf(l1 - l0));
      sel_i[0] = i0; sel_i[1] = i1;
      sel_f[0] = w0; sel_f[1] = 1.f - w0;
    }
    __syncthreads();
  }
  int e0 = sel_i[0], e1 = sel_i[1];
  float w0 = sel_f[0], w1 = sel_f[1];

  for (int i = tid; i < DIM; i += 256) cnt[i] = 0;
  __syncthreads();
  for (int k = tid; k < 2 * NFRQ; k += 256) {
    int t = k >> 11, j = k & (NFRQ - 1);
    int e = t ? e1 : e0;
    int f = lidx[e * NFRQ + j];
    atomicAdd(&cnt[f / DIM], 1);
  }
  __syncthreads();
  {  // parallel exclusive scan of cnt[768]: 3 per thread
    int s0 = cnt[3 * tid], s1 = cnt[3 * tid + 1], s2 = cnt[3 * tid + 2];
    int sum = s0 + s1 + s2;
    int lane = tid & 63, wid = tid >> 6;
    int v = sum;
#pragma unroll
    for (int d = 1; d < 64; d <<= 1) {
      int u = __shfl_up(v, d);
      if (lane >= d) v += u;
    }
    if (lane == 63) wsum[wid] = v;
    __syncthreads();
    int woff = 0;
#pragma unroll
    for (int w = 0; w < 4; ++w) if (w < wid) woff += wsum[w];
    int excl = woff + v - sum;
    int* rsg = row_start + b * (DIM + 1);
    base[3 * tid]     = excl;
    base[3 * tid + 1] = excl + s0;
    base[3 * tid + 2] = excl + s0 + s1;
    rsg[3 * tid]     = excl;
    rsg[3 * tid + 1] = excl + s0;
    rsg[3 * tid + 2] = excl + s0 + s1;
    if (tid == 255) rsg[DIM] = excl + sum;   // == 4096
  }
  __syncthreads();
  for (int i = tid; i < DIM; i += 256) cnt[i] = 0;
  __syncthreads();
  for (int k = tid; k < 2 * NFRQ; k += 256) {
    int t = k >> 11, j = k & (NFRQ - 1);
    int e = t ? e1 : e0;
    float w = t ? w1 : w0;
    int f = lidx[e * NFRQ + j];
    int r = f / DIM, c = f - r * DIM;
    int pos = base[r] + atomicAdd(&cnt[r], 1);
    // per-nz rotation constant for x -> x+64: angle 2pi*64c/768
    float cf = (float)c;
    float rv = (cf * 64.0f) * INV768;   // 64c < 2^24 exact; /768 ~exact
    float fr, c64, s64;
    asm("v_fract_f32 %0, %1" : "=v"(fr) : "v"(rv));
    asm("v_cos_f32 %0, %1" : "=v"(c64) : "v"(fr));
    asm("v_sin_f32 %0, %1" : "=v"(s64) : "v"(fr));
    s_cv[b * 4096 + pos] = make_float4(cf, coeff[e * NFRQ + j] * w * SCALE, c64, s64);
  }
}

// ---------------------------------------------------------------------------
// Kernel B (v9): stage-1 trig-by-rotation. 8 waves x 8 streams; lane owns
// x = {xg*192+lane, +64, +128}. Per stream-k: ONE fract/sin/cos (for x0) +
// two rotations by the per-nz constant (c64,s64) -> trans work per nz drops
// 18 -> 6 vs v8. LDS [4][32][196] (50KB); flush keeps full-64B-line writes.
// Grid (12 rg, 2 xg, 32 b) = 768 blocks x 512 thr (3 blocks/CU).
// ---------------------------------------------------------------------------
__global__ __launch_bounds__(512, 2) void stage1_kernel(const int* __restrict__ row_start,
                                                        const float4* __restrict__ s_cv,
                                                        __hip_bfloat16* __restrict__ BT) {
  int b = blockIdx.z;
  int xg = blockIdx.y;                  // 0..1 (x-chunk of 192)
  int rg = blockIdx.x;                  // 0..11 (32 pair-rows)
  int tid = threadIdx.x;                // 512
  int lane = tid & 63, w = tid >> 6;    // w in 0..7
  __shared__ __hip_bfloat16 lds[4][32][196];   // 0:ReP 1:-ImP 2:ReM 3:-ImM
  const int* rs = row_start + b * (DIM + 1);
  const float4* cv = s_cv + b * 4096;
  int rowBase = rg * 32;
  float xf = (float)(xg * 192 + lane);  // this lane's base x

  int pbase = rowBase + w * 4;
  int sstart[8], scount[8];
#pragma unroll
  for (int s = 0; s < 8; ++s) {
    int row = pbase + (s >> 1) + (s & 1) * 384;
    int st = rs[row];
    sstart[s] = st;
    scount[s] = rs[row + 1] - st;
  }
  int kmax = 0;
#pragma unroll
  for (int s = 0; s < 8; ++s) kmax = scount[s] > kmax ? scount[s] : kmax;

  float acc[8][6];    // {re,im} for x0, x0+64, x0+128 (im = +sum v*sin)
#pragma unroll
  for (int s = 0; s < 8; ++s)
#pragma unroll
    for (int m = 0; m < 6; ++m) acc[s][m] = 0.f;

  float4 c[8];
#pragma unroll
  for (int s = 0; s < 8; ++s) {
    int idx = sstart[s] < 4095 ? sstart[s] : 4095;
    c[s] = cv[idx];
  }

  for (int k = 0; k < kmax; ++k) {
    float4 cn[8];
#pragma unroll
    for (int s = 0; s < 8; ++s) {
      int kk = (k + 1) < scount[s] ? (k + 1) : 0;     // cndmask, no branch
      int idx = sstart[s] + kk;
      idx = idx < 4095 ? idx : 4095;
      cn[s] = cv[idx];
    }
#pragma unroll
    for (int s = 0; s < 8; ++s) {
      float v = k < scount[s] ? c[s].y : 0.f;         // cndmask, no branch
      float r0 = (c[s].x * xf) * INV768;              // integer product, exact
      float f0, sn, cs;
      asm("v_fract_f32 %0, %1" : "=v"(f0) : "v"(r0));
      asm("v_sin_f32 %0, %1" : "=v"(sn) : "v"(f0));
      asm("v_cos_f32 %0, %1" : "=v"(cs) : "v"(f0));
      float c64 = c[s].z, s64 = c[s].w;
      acc[s][0] += v * cs; acc[s][1] += v * sn;       // x0
      float cs1 = cs * c64 - sn * s64;
      float sn1 = sn * c64 + cs * s64;
      acc[s][2] += v * cs1; acc[s][3] += v * sn1;     // x0+64
      float cs2 = cs1 * c64 - sn1 * s64;
      float sn2 = sn1 * c64 + cs1 * s64;
      acc[s][4] += v * cs2; acc[s][5] += v * sn2;     // x0+128
    }
#pragma unroll
    for (int s = 0; s < 8; ++s) c[s] = cn[s];
  }

  // combine P = A+B, M = A-B per pair q: A = stream 2q, B = stream 2q+1
#pragma unroll
  for (int q = 0; q < 4; ++q) {
    int slot = w * 4 + q;
    const float* aa = acc[2 * q];
    const float* bb = acc[2 * q + 1];
#pragma unroll
    for (int m = 0; m < 3; ++m) {
      int x = lane + 64 * m;
      lds[0][slot][x] = __float2bfloat16(aa[2 * m] + bb[2 * m]);          // ReP
      lds[1][slot][x] = __float2bfloat16(-(aa[2 * m + 1] + bb[2 * m + 1])); // -ImP
      lds[2][slot][x] = __float2bfloat16(aa[2 * m] - bb[2 * m]);          // ReM
      lds[3][slot][x] = __float2bfloat16(-(aa[2 * m + 1] - bb[2 * m + 1])); // -ImM
    }
  }
  __syncthreads();
  // flush: 4 arrays x 192 x = 768 tasks; each writes one FULL 64B line
  for (int i = tid; i < 4 * 192; i += 512) {
    int a = i / 192, x = i - a * 192;
    union { ushort h[32]; uint4 v[4]; } u;
#pragma unroll
    for (int k = 0; k < 32; ++k) u.h[k] = *(const ushort*)&lds[a][k][x];
    __hip_bfloat16* dst = BT + ((size_t)(b * HALF + xg * 192 + x)) * KROW + a * HALF + rowBase;
#pragma unroll
    for (int q = 0; q < 4; ++q) *(uint4*)(dst + q * 8) = u.v[q];
  }
}

// ---------------------------------------------------------------------------
// Kernel C: nyq blocks (bid<128) + parity quadrant GEMM  [unchanged except
// s_cv is float4]. BK=64, 12 steps, dbuf + __syncthreads, 8-slot XOR swizzle.
// ---------------------------------------------------------------------------
__device__ inline void gload_lds16(const void* g, void* l) {
  __builtin_amdgcn_global_load_lds((const __attribute__((address_space(1))) void*)g,
                                   (__attribute__((address_space(3))) void*)l, 16, 0, 0);
}

__global__ __launch_bounds__(256) void gemm_kernel(const __hip_bfloat16* __restrict__ A,
                                                   const __hip_bfloat16* __restrict__ BT,
                                                   const int* __restrict__ row_start,
                                                   const float4* __restrict__ s_cv,
                                                   float* __restrict__ C) {
  int bid = blockIdx.x;
  int tid = threadIdx.x;
  __shared__ __align__(16) __hip_bfloat16 As[2][64 * 64];   // 16KB
  __shared__ __align__(16) __hip_bfloat16 Bs[2][64 * 64];   // 16KB

  if (bid < 4 * NB) {                 // ---- Nyquist blocks ----
    int slice = bid & 3, b = bid >> 2;
    float* ob = C + (size_t)b * DIM * DIM;
    if (slice == 3) {                 // row y=384: sum_rp (-1)^rp ReP[rp,x]
      for (int x = tid; x < HALF; x += 256) {
        const __hip_bfloat16* btx = BT + ((size_t)(b * HALF + x)) * KROW;
        float acc = 0.f;
        for (int r = 0; r < HALF; r += 8) {
          union { uint4 v4; __hip_bfloat16 h[8]; } u;
          u.v4 = *(const uint4*)(btx + r);
#pragma unroll
          for (int q = 0; q < 8; ++q) {
            float v = __bfloat162float(u.h[q]);
            acc += (q & 1) ? -v : v;
          }
        }
        int xm = x ? DIM - x : 0;
        ob[(size_t)HALF * DIM + x]  = acc;
        ob[(size_t)HALF * DIM + xm] = acc;
      }
      return;
    }
    // slices 0..2: column x=384
    float* Re384 = (float*)As;        // reuse LDS
    const int* rs = row_start + b * (DIM + 1);
    const float4* cv = s_cv + b * 4096;
    for (int r = tid; r < DIM; r += 256) {
      int s = rs[r], e = rs[r + 1];
      float acc = 0.f;
      for (int p = s; p < e; ++p) {
        float4 c = cv[p];
        int ci = (int)c.x;
        acc += (ci & 1) ? -c.y : c.y;
      }
      Re384[r] = acc;
    }
    __syncthreads();
    int y = slice * 129 + tid;
    if (tid < 129 && y <= HALF) {
      float yf = (float)y;
      float a0 = 0.f, a1 = 0.f, a2 = 0.f, a3 = 0.f;
      for (int r = 0; r < DIM; r += 4) {
        float f0, f1, f2, f3, c0, c1, c2, c3;
        float v0 = (yf * (float)(r + 0)) * INV768;
        float v1 = (yf * (float)(r + 1)) * INV768;
        float v2 = (yf * (float)(r + 2)) * INV768;
        float v3 = (yf * (float)(r + 3)) * INV768;
        asm("v_fract_f32 %0, %1" : "=v"(f0) : "v"(v0));
        asm("v_fract_f32 %0, %1" : "=v"(f1) : "v"(v1));
        asm("v_fract_f32 %0, %1" : "=v"(f2) : "v"(v2));
        asm("v_fract_f32 %0, %1" : "=v"(f3) : "v"(v3));
        asm("v_cos_f32 %0, %1" : "=v"(c0) : "v"(f0));
        asm("v_cos_f32 %0, %1" : "=v"(c1) : "v"(f1));
        asm("v_cos_f32 %0, %1" : "=v"(c2) : "v"(f2));
        asm("v_cos_f32 %0, %1" : "=v"(c3) : "v"(f3));
        a0 += Re384[r + 0] * c0;
        a1 += Re384[r + 1] * c1;
        a2 += Re384[r + 2] * c2;
        a3 += Re384[r + 3] * c3;
      }
      float acc = (a0 + a1) + (a2 + a3);
      int ym = y ? DIM - y : 0;
      ob[(size_t)y  * DIM + HALF] = acc;
      ob[(size_t)ym * DIM + HALF] = acc;
    }
    return;
  }

  // ---- GEMM blocks: 1152 = 8*144; 36 tiles/batch = 2 par x 6 bx x 3 by ----
  int gbid = bid - 4 * NB;
  int swz = (gbid & 7) * 144 + (gbid >> 3);
  int b = swz / 36; int rem = swz - b * 36;
  int par = rem / 18; int r2 = rem - par * 18;
  int bx = r2 / 3, by = r2 % 3;

  float* Cp = C + (size_t)b * DIM * DIM;
  int y0 = by * 64, x0 = bx * 64;     // y0 in t-space [0,192)

  int wv = tid >> 6, lane = tid & 63;
  int wr = wv >> 1, wc = wv & 1;      // wave: 32x32 sub-tile
  int lhi = lane >> 4, llo = lane & 15;

  int c0 = tid, c1 = tid + 256;
  int row0 = c0 >> 3, row1 = c1 >> 3;
  int so0 = (((c0 & 7) ^ (row0 & 7))) * 8;
  int so1 = (((c1 & 7) ^ (row1 & 7))) * 8;

  f32x4 acc1[2][2] = {};
  f32x4 acc2[2][2] = {};

  const __hip_bfloat16* A0 = A  + ((size_t)(par * 192 + y0 + row0)) * KG + so0;
  const __hip_bfloat16* A1 = A  + ((size_t)(par * 192 + y0 + row1)) * KG + so1;
  const __hip_bfloat16* B0 = BT + ((size_t)(b * HALF + x0 + row0)) * KROW + par * KG + so0;
  const __hip_bfloat16* B1 = BT + ((size_t)(b * HALF + x0 + row1)) * KROW + par * KG + so1;

  gload_lds16(A0, As[0] + c0 * 8);
  gload_lds16(A1, As[0] + c1 * 8);
  gload_lds16(B0, Bs[0] + c0 * 8);
  gload_lds16(B1, Bs[0] + c1 * 8);
  __syncthreads();

  auto step = [&](int t, f32x4 (&acc)[2][2], bool last) {
    int cur = t & 1;
    if (!last) {
      int ktn = (t + 1) * 64;
      gload_lds16(A0 + ktn, As[cur ^ 1] + c0 * 8);
      gload_lds16(A1 + ktn, As[cur ^ 1] + c1 * 8);
      gload_lds16(B0 + ktn, Bs[cur ^ 1] + c0 * 8);
      gload_lds16(B1 + ktn, Bs[cur ^ 1] + c1 * 8);
    }
    bf16x8 af[2][2], bfr[2][2];
#pragma unroll
    for (int i = 0; i < 2; ++i)
#pragma unroll
      for (int kh = 0; kh < 2; ++kh) {
        int row = wr * 32 + i * 16 + llo;
        int phys = ((lhi + 4 * kh) ^ (llo & 7)) * 8;
        af[i][kh] = *(const bf16x8*)(As[cur] + row * 64 + phys);
      }
#pragma unroll
    for (int j = 0; j < 2; ++j)
#pragma unroll
      for (int kh = 0; kh < 2; ++kh) {
        int row = wc * 32 + j * 16 + llo;
        int phys = ((lhi + 4 * kh) ^ (llo & 7)) * 8;
        bfr[j][kh] = *(const bf16x8*)(Bs[cur] + row * 64 + phys);
      }
#pragma unroll
    for (int kh = 0; kh < 2; ++kh)
#pragma unroll
      for (int i = 0; i < 2; ++i)
#pragma unroll
        for (int j = 0; j < 2; ++j)
          acc[i][j] = __builtin_amdgcn_mfma_f32_16x16x32_bf16(af[i][kh], bfr[j][kh],
                                                              acc[i][j], 0, 0, 0);
    if (!last) __syncthreads();
  };

  for (int t = 0; t < 6; ++t)  step(t, acc1, false);       // cos half
  for (int t = 6; t < 12; ++t) step(t, acc2, t == 11);     // sin half

#pragma unroll
  for (int i = 0; i < 2; ++i) {
#pragma unroll
    for (int j = 0; j < 2; ++j) {
      int x = x0 + wc * 32 + j * 16 + llo;
      int xm = x ? DIM - x : 0;
#pragma unroll
      for (int q = 0; q < 4; ++q) {
        int tt = y0 + wr * 32 + i * 16 + lhi * 4 + q;
        int y = 2 * tt + par;
        int ym = y ? DIM - y : 0;
        float c1 = acc1[i][j][q], c2 = acc2[i][j][q];
        float vd = c1 + c2;
        float vs = c1 - c2;
        Cp[(size_t)y  * DIM + x]  = vd;
        Cp[(size_t)ym * DIM + xm] = vd;
        Cp[(size_t)y  * DIM + xm] = vs;
        Cp[(size_t)ym * DIM + x]  = vs;
      }
    }
  }
}

// ---------------------------------------------------------------------------
extern "C" void kernel_launch(void* const* d_in, const int* in_sizes, int n_in,
                              void* d_out, int out_size, void* d_ws, size_t ws_size,
                              hipStream_t stream) {
  const float* cls   = (const float*)d_in[0];
  const float* Wr    = (const float*)d_in[1];
  const float* br    = (const float*)d_in[2];
  const float* coeff = (const float*)d_in[3];
  const int*   lidx  = (const int*)d_in[4];
  float* out = (float*)d_out;

  char* ws = (char*)d_ws;
  int*    row_start = (int*)(ws + 0);           //    98,432
  float4* s_cv      = (float4*)(ws + 98944);    // 2,097,152 (ends 2,196,096)
  __hip_bfloat16* A  = (__hip_bfloat16*)(ws + 2196096);  // 589,824 (ends 2,785,920)
  __hip_bfloat16* BT = (__hip_bfloat16*)(ws + 2785920);  // 37,748,736 (~40.5 MB)

  prep_kernel<<<32 + 384, 256, 0, stream>>>(cls, Wr, br, coeff, lidx,
                                            row_start, s_cv, A);
  stage1_kernel<<<dim3(12, 2, NB), 512, 0, stream>>>(row_start, s_cv, BT);
  gemm_kernel<<<4 * NB + 1152, 256, 0, stream>>>(A, BT, row_start, s_cv, out);
}

// Round 20
// 101.421 us; speedup vs baseline: 1.2573x; 1.0471x over previous
//
#include <hip/hip_runtime.h>
#include <hip/hip_bf16.h>

#define DIM 768
#define NE 64
#define NFRQ 2048
#define NB 32
#define HALF 384                // computed quadrant extent (y,x in [0,384))
#define KROW 1536               // BT per-x row elems: [ReP|-ImP|ReM|-ImM] x 384
#define KG 768                  // GEMM K per parity (384 cos + 384 sin)
#define TWO_PI 6.283185307179586f
#define INV768 (1.0f / 768.0f)
#define SCALE (300.0f / (float)(DIM * DIM))   // ALPHA / (dim*dim), folded into values

typedef __attribute__((ext_vector_type(8))) short bf16x8;   // 8 bf16 (4 VGPRs)
typedef __attribute__((ext_vector_type(4))) float f32x4;    // MFMA accumulator

// ---------------------------------------------------------------------------
// Kernel A "prep" (one launch, 2 roles by blockIdx):
//  bid < 32   : fused router + bucket-sort build;
//               s_cv = float4(colf, weighted val, cos(2pi*64c/768), sin(...))
//  bid >= 32  : A twiddle row idx = bid-32 (parity layout)
// ---------------------------------------------------------------------------
__global__ __launch_bounds__(256) void prep_kernel(const float* __restrict__ cls,
                                                   const float* __restrict__ W,
                                                   const float* __restrict__ bias,
                                                   const float* __restrict__ coeff,
                                                   const int* __restrict__ lidx,
                                                   int* __restrict__ row_start,
                                                   float4* __restrict__ s_cv,
                                                   __hip_bfloat16* __restrict__ A) {
  int bid = blockIdx.x;
  int tid = threadIdx.x;

  if (bid >= 32) {                    // ---- A twiddle rows (parity layout) ----
    int idx = bid - 32;               // 0..383 ; row idx = par*192 + t
    int y = 2 * (idx % 192) + (idx / 192);
    if (tid < 96) {
      int r0 = tid * 4;
      union { __hip_bfloat16 h[4]; ushort4 v; } uc, us;
#pragma unroll
      for (int j = 0; j < 4; ++j) {
        int m = (y * (r0 + j)) % DIM;
        float s, c;
        sincosf((TWO_PI / (float)DIM) * (float)m, &s, &c);
        uc.h[j] = __float2bfloat16(c);
        us.h[j] = __float2bfloat16(s);
      }
      *(ushort4*)(A + (size_t)idx * KG + r0)        = uc.v;
      *(ushort4*)(A + (size_t)idx * KG + HALF + r0) = us.v;
    }
    return;
  }

  // ---- router + build, batch b = bid ----
  int b = bid;
  __shared__ int cnt[DIM];
  __shared__ int base[DIM];
  __shared__ int wsum[4];
  __shared__ int sel_i[2];
  __shared__ float sel_f[2];
  float* part   = (float*)cnt;
  float* logits = (float*)base;

  {
    int e = tid & 63, q = tid >> 6;
    const float* c = cls + b * DIM + q * 192;
    const float* w = W + e * DIM + q * 192;
    float acc = 0.f;
#pragma unroll 4
    for (int i = 0; i < 192; i += 4) {
      float4 cv4 = *(const float4*)(c + i);
      float4 wv4 = *(const float4*)(w + i);
      acc += cv4.x * wv4.x + cv4.y * wv4.y + cv4.z * wv4.z + cv4.w * wv4.w;
    }
    part[q * 64 + e] = acc;
    __syncthreads();
    if (tid < NE)
      logits[tid] = part[tid] + part[64 + tid] + part[128 + tid] + part[192 + tid] + bias[tid];
    __syncthreads();
    if (tid == 0) {
      int i0 = 0; float l0 = logits[0];
      for (int i = 1; i < NE; ++i) { float v = logits[i]; if (v > l0) { l0 = v; i0 = i; } }
      int i1 = -1; float l1 = -3.4e38f;
      for (int i = 0; i < NE; ++i) {
        if (i == i0) continue;
        float v = logits[i]; if (v > l1) { l1 = v; i1 = i; }
      }
      float w0 = 1.f / (1.f + expf(l1 - l0));
      sel_i[0] = i0; sel_i[1] = i1;
      sel_f[0] = w0; sel_f[1] = 1.f - w0;
    }
    __syncthreads();
  }
  int e0 = sel_i[0], e1 = sel_i[1];
  float w0 = sel_f[0], w1 = sel_f[1];

  for (int i = tid; i < DIM; i += 256) cnt[i] = 0;
  __syncthreads();
  for (int k = tid; k < 2 * NFRQ; k += 256) {
    int t = k >> 11, j = k & (NFRQ - 1);
    int e = t ? e1 : e0;
    int f = lidx[e * NFRQ + j];
    atomicAdd(&cnt[f / DIM], 1);
  }
  __syncthreads();
  {  // parallel exclusive scan of cnt[768]: 3 per thread
    int s0 = cnt[3 * tid], s1 = cnt[3 * tid + 1], s2 = cnt[3 * tid + 2];
    int sum = s0 + s1 + s2;
    int lane = tid & 63, wid = tid >> 6;
    int v = sum;
#pragma unroll
    for (int d = 1; d < 64; d <<= 1) {
      int u = __shfl_up(v, d);
      if (lane >= d) v += u;
    }
    if (lane == 63) wsum[wid] = v;
    __syncthreads();
    int woff = 0;
#pragma unroll
    for (int w = 0; w < 4; ++w) if (w < wid) woff += wsum[w];
    int excl = woff + v - sum;
    int* rsg = row_start + b * (DIM + 1);
    base[3 * tid]     = excl;
    base[3 * tid + 1] = excl + s0;
    base[3 * tid + 2] = excl + s0 + s1;
    rsg[3 * tid]     = excl;
    rsg[3 * tid + 1] = excl + s0;
    rsg[3 * tid + 2] = excl + s0 + s1;
    if (tid == 255) rsg[DIM] = excl + sum;   // == 4096
  }
  __syncthreads();
  for (int i = tid; i < DIM; i += 256) cnt[i] = 0;
  __syncthreads();
  for (int k = tid; k < 2 * NFRQ; k += 256) {
    int t = k >> 11, j = k & (NFRQ - 1);
    int e = t ? e1 : e0;
    float w = t ? w1 : w0;
    int f = lidx[e * NFRQ + j];
    int r = f / DIM, c = f - r * DIM;
    int pos = base[r] + atomicAdd(&cnt[r], 1);
    // per-nz rotation constant for x -> x+64: angle 2pi*64c/768
    float cf = (float)c;
    float rv = (cf * 64.0f) * INV768;   // 64c < 2^24 exact
    float fr, c64, s64;
    asm("v_fract_f32 %0, %1" : "=v"(fr) : "v"(rv));
    asm("v_cos_f32 %0, %1" : "=v"(c64) : "v"(fr));
    asm("v_sin_f32 %0, %1" : "=v"(s64) : "v"(fr));
    s_cv[b * 4096 + pos] = make_float4(cf, coeff[e * NFRQ + j] * w * SCALE, c64, s64);
  }
}

// ---------------------------------------------------------------------------
// Kernel B (v10): stage-1 trig-by-rotation, SEQUENTIAL PAIRS. Wave owns 4
// pairs as before, but processes them one at a time with 2 streams (row rp,
// row rp+384): k-loop runs to max(nA,nB) ~= 6.6 instead of kmax-of-8 ~= 11.5
// -> executed trig/FMA work drops 1.75x (the v9 waste). cv prefetch + 6-trans
// body keeps the 2 wave-uniform L1 loads hidden.
// ---------------------------------------------------------------------------
__global__ __launch_bounds__(512, 2) void stage1_kernel(const int* __restrict__ row_start,
                                                        const float4* __restrict__ s_cv,
                                                        __hip_bfloat16* __restrict__ BT) {
  int b = blockIdx.z;
  int xg = blockIdx.y;                  // 0..1 (x-chunk of 192)
  int rg = blockIdx.x;                  // 0..11 (32 pair-rows)
  int tid = threadIdx.x;                // 512
  int lane = tid & 63, w = tid >> 6;    // w in 0..7
  __shared__ __hip_bfloat16 lds[4][32][196];   // 0:ReP 1:-ImP 2:ReM 3:-ImM
  const int* rs = row_start + b * (DIM + 1);
  const float4* cv = s_cv + b * 4096;
  int rowBase = rg * 32;
  float xf = (float)(xg * 192 + lane);  // this lane's base x

  int pbase = rowBase + w * 4;
  int rbA[5], rbB[5];
#pragma unroll
  for (int t = 0; t < 5; ++t) {
    rbA[t] = rs[pbase + t];
    rbB[t] = rs[pbase + 384 + t];
  }

#pragma unroll
  for (int q = 0; q < 4; ++q) {
    int sA = rbA[q], nA = rbA[q + 1] - sA;
    int sB = rbB[q], nB = rbB[q + 1] - sB;
    int kq = nA > nB ? nA : nB;
    float aA[6], aB[6];
#pragma unroll
    for (int m = 0; m < 6; ++m) { aA[m] = 0.f; aB[m] = 0.f; }

    float4 cA = cv[sA < 4095 ? sA : 4095];
    float4 cB = cv[sB < 4095 ? sB : 4095];
    for (int k = 0; k < kq; ++k) {
      // prefetch next cv for both streams (branchless)
      int kkA = (k + 1) < nA ? (k + 1) : 0;
      int kkB = (k + 1) < nB ? (k + 1) : 0;
      int iA = sA + kkA; iA = iA < 4095 ? iA : 4095;
      int iB = sB + kkB; iB = iB < 4095 ? iB : 4095;
      float4 cAn = cv[iA];
      float4 cBn = cv[iB];
      // stream A
      {
        float v = k < nA ? cA.y : 0.f;
        float r0 = (cA.x * xf) * INV768;
        float f0, sn, cs;
        asm("v_fract_f32 %0, %1" : "=v"(f0) : "v"(r0));
        asm("v_sin_f32 %0, %1" : "=v"(sn) : "v"(f0));
        asm("v_cos_f32 %0, %1" : "=v"(cs) : "v"(f0));
        float c64 = cA.z, s64 = cA.w;
        aA[0] += v * cs; aA[1] += v * sn;
        float cs1 = cs * c64 - sn * s64;
        float sn1 = sn * c64 + cs * s64;
        aA[2] += v * cs1; aA[3] += v * sn1;
        float cs2 = cs1 * c64 - sn1 * s64;
        float sn2 = sn1 * c64 + cs1 * s64;
        aA[4] += v * cs2; aA[5] += v * sn2;
      }
      // stream B
      {
        float v = k < nB ? cB.y : 0.f;
        float r0 = (cB.x * xf) * INV768;
        float f0, sn, cs;
        asm("v_fract_f32 %0, %1" : "=v"(f0) : "v"(r0));
        asm("v_sin_f32 %0, %1" : "=v"(sn) : "v"(f0));
        asm("v_cos_f32 %0, %1" : "=v"(cs) : "v"(f0));
        float c64 = cB.z, s64 = cB.w;
        aB[0] += v * cs; aB[1] += v * sn;
        float cs1 = cs * c64 - sn * s64;
        float sn1 = sn * c64 + cs * s64;
        aB[2] += v * cs1; aB[3] += v * sn1;
        float cs2 = cs1 * c64 - sn1 * s64;
        float sn2 = sn1 * c64 + cs1 * s64;
        aB[4] += v * cs2; aB[5] += v * sn2;
      }
      cA = cAn; cB = cBn;
    }
    // combine P = A+B, M = A-B; write bf16 to LDS (slot = w*4+q)
    int slot = w * 4 + q;
#pragma unroll
    for (int m = 0; m < 3; ++m) {
      int x = lane + 64 * m;
      lds[0][slot][x] = __float2bfloat16(aA[2 * m] + aB[2 * m]);            // ReP
      lds[1][slot][x] = __float2bfloat16(-(aA[2 * m + 1] + aB[2 * m + 1])); // -ImP
      lds[2][slot][x] = __float2bfloat16(aA[2 * m] - aB[2 * m]);            // ReM
      lds[3][slot][x] = __float2bfloat16(-(aA[2 * m + 1] - aB[2 * m + 1])); // -ImM
    }
  }
  __syncthreads();
  // flush: 4 arrays x 192 x = 768 tasks; each writes one FULL 64B line
  for (int i = tid; i < 4 * 192; i += 512) {
    int a = i / 192, x = i - a * 192;
    union { ushort h[32]; uint4 v[4]; } u;
#pragma unroll
    for (int k = 0; k < 32; ++k) u.h[k] = *(const ushort*)&lds[a][k][x];
    __hip_bfloat16* dst = BT + ((size_t)(b * HALF + xg * 192 + x)) * KROW + a * HALF + rowBase;
#pragma unroll
    for (int q = 0; q < 4; ++q) *(uint4*)(dst + q * 8) = u.v[q];
  }
}

// ---------------------------------------------------------------------------
// Kernel C: nyq blocks (bid<128) + parity quadrant GEMM  [unchanged]
// BK=64, 12 steps, dbuf + __syncthreads, 8-slot XOR swizzle.
// ---------------------------------------------------------------------------
__device__ inline void gload_lds16(const void* g, void* l) {
  __builtin_amdgcn_global_load_lds((const __attribute__((address_space(1))) void*)g,
                                   (__attribute__((address_space(3))) void*)l, 16, 0, 0);
}

__global__ __launch_bounds__(256) void gemm_kernel(const __hip_bfloat16* __restrict__ A,
                                                   const __hip_bfloat16* __restrict__ BT,
                                                   const int* __restrict__ row_start,
                                                   const float4* __restrict__ s_cv,
                                                   float* __restrict__ C) {
  int bid = blockIdx.x;
  int tid = threadIdx.x;
  __shared__ __align__(16) __hip_bfloat16 As[2][64 * 64];   // 16KB
  __shared__ __align__(16) __hip_bfloat16 Bs[2][64 * 64];   // 16KB

  if (bid < 4 * NB) {                 // ---- Nyquist blocks ----
    int slice = bid & 3, b = bid >> 2;
    float* ob = C + (size_t)b * DIM * DIM;
    if (slice == 3) {                 // row y=384: sum_rp (-1)^rp ReP[rp,x]
      for (int x = tid; x < HALF; x += 256) {
        const __hip_bfloat16* btx = BT + ((size_t)(b * HALF + x)) * KROW;
        float acc = 0.f;
        for (int r = 0; r < HALF; r += 8) {
          union { uint4 v4; __hip_bfloat16 h[8]; } u;
          u.v4 = *(const uint4*)(btx + r);
#pragma unroll
          for (int q = 0; q < 8; ++q) {
            float v = __bfloat162float(u.h[q]);
            acc += (q & 1) ? -v : v;
          }
        }
        int xm = x ? DIM - x : 0;
        ob[(size_t)HALF * DIM + x]  = acc;
        ob[(size_t)HALF * DIM + xm] = acc;
      }
      return;
    }
    // slices 0..2: column x=384
    float* Re384 = (float*)As;        // reuse LDS
    const int* rs = row_start + b * (DIM + 1);
    const float4* cv = s_cv + b * 4096;
    for (int r = tid; r < DIM; r += 256) {
      int s = rs[r], e = rs[r + 1];
      float acc = 0.f;
      for (int p = s; p < e; ++p) {
        float4 c = cv[p];
        int ci = (int)c.x;
        acc += (ci & 1) ? -c.y : c.y;
      }
      Re384[r] = acc;
    }
    __syncthreads();
    int y = slice * 129 + tid;
    if (tid < 129 && y <= HALF) {
      float yf = (float)y;
      float a0 = 0.f, a1 = 0.f, a2 = 0.f, a3 = 0.f;
      for (int r = 0; r < DIM; r += 4) {
        float f0, f1, f2, f3, c0, c1, c2, c3;
        float v0 = (yf * (float)(r + 0)) * INV768;
        float v1 = (yf * (float)(r + 1)) * INV768;
        float v2 = (yf * (float)(r + 2)) * INV768;
        float v3 = (yf * (float)(r + 3)) * INV768;
        asm("v_fract_f32 %0, %1" : "=v"(f0) : "v"(v0));
        asm("v_fract_f32 %0, %1" : "=v"(f1) : "v"(v1));
        asm("v_fract_f32 %0, %1" : "=v"(f2) : "v"(v2));
        asm("v_fract_f32 %0, %1" : "=v"(f3) : "v"(v3));
        asm("v_cos_f32 %0, %1" : "=v"(c0) : "v"(f0));
        asm("v_cos_f32 %0, %1" : "=v"(c1) : "v"(f1));
        asm("v_cos_f32 %0, %1" : "=v"(c2) : "v"(f2));
        asm("v_cos_f32 %0, %1" : "=v"(c3) : "v"(f3));
        a0 += Re384[r + 0] * c0;
        a1 += Re384[r + 1] * c1;
        a2 += Re384[r + 2] * c2;
        a3 += Re384[r + 3] * c3;
      }
      float acc = (a0 + a1) + (a2 + a3);
      int ym = y ? DIM - y : 0;
      ob[(size_t)y  * DIM + HALF] = acc;
      ob[(size_t)ym * DIM + HALF] = acc;
    }
    return;
  }

  // ---- GEMM blocks: 1152 = 8*144; 36 tiles/batch = 2 par x 6 bx x 3 by ----
  int gbid = bid - 4 * NB;
  int swz = (gbid & 7) * 144 + (gbid >> 3);
  int b = swz / 36; int rem = swz - b * 36;
  int par = rem / 18; int r2 = rem - par * 18;
  int bx = r2 / 3, by = r2 % 3;

  float* Cp = C + (size_t)b * DIM * DIM;
  int y0 = by * 64, x0 = bx * 64;     // y0 in t-space [0,192)

  int wv = tid >> 6, lane = tid & 63;
  int wr = wv >> 1, wc = wv & 1;      // wave: 32x32 sub-tile
  int lhi = lane >> 4, llo = lane & 15;

  int c0 = tid, c1 = tid + 256;
  int row0 = c0 >> 3, row1 = c1 >> 3;
  int so0 = (((c0 & 7) ^ (row0 & 7))) * 8;
  int so1 = (((c1 & 7) ^ (row1 & 7))) * 8;

  f32x4 acc1[2][2] = {};
  f32x4 acc2[2][2] = {};

  const __hip_bfloat16* A0 = A  + ((size_t)(par * 192 + y0 + row0)) * KG + so0;
  const __hip_bfloat16* A1 = A  + ((size_t)(par * 192 + y0 + row1)) * KG + so1;
  const __hip_bfloat16* B0 = BT + ((size_t)(b * HALF + x0 + row0)) * KROW + par * KG + so0;
  const __hip_bfloat16* B1 = BT + ((size_t)(b * HALF + x0 + row1)) * KROW + par * KG + so1;

  gload_lds16(A0, As[0] + c0 * 8);
  gload_lds16(A1, As[0] + c1 * 8);
  gload_lds16(B0, Bs[0] + c0 * 8);
  gload_lds16(B1, Bs[0] + c1 * 8);
  __syncthreads();

  auto step = [&](int t, f32x4 (&acc)[2][2], bool last) {
    int cur = t & 1;
    if (!last) {
      int ktn = (t + 1) * 64;
      gload_lds16(A0 + ktn, As[cur ^ 1] + c0 * 8);
      gload_lds16(A1 + ktn, As[cur ^ 1] + c1 * 8);
      gload_lds16(B0 + ktn, Bs[cur ^ 1] + c0 * 8);
      gload_lds16(B1 + ktn, Bs[cur ^ 1] + c1 * 8);
    }
    bf16x8 af[2][2], bfr[2][2];
#pragma unroll
    for (int i = 0; i < 2; ++i)
#pragma unroll
      for (int kh = 0; kh < 2; ++kh) {
        int row = wr * 32 + i * 16 + llo;
        int phys = ((lhi + 4 * kh) ^ (llo & 7)) * 8;
        af[i][kh] = *(const bf16x8*)(As[cur] + row * 64 + phys);
      }
#pragma unroll
    for (int j = 0; j < 2; ++j)
#pragma unroll
      for (int kh = 0; kh < 2; ++kh) {
        int row = wc * 32 + j * 16 + llo;
        int phys = ((lhi + 4 * kh) ^ (llo & 7)) * 8;
        bfr[j][kh] = *(const bf16x8*)(Bs[cur] + row * 64 + phys);
      }
#pragma unroll
    for (int kh = 0; kh < 2; ++kh)
#pragma unroll
      for (int i = 0; i < 2; ++i)
#pragma unroll
        for (int j = 0; j < 2; ++j)
          acc[i][j] = __builtin_amdgcn_mfma_f32_16x16x32_bf16(af[i][kh], bfr[j][kh],
                                                              acc[i][j], 0, 0, 0);
    if (!last) __syncthreads();
  };

  for (int t = 0; t < 6; ++t)  step(t, acc1, false);       // cos half
  for (int t = 6; t < 12; ++t) step(t, acc2, t == 11);     // sin half

#pragma unroll
  for (int i = 0; i < 2; ++i) {
#pragma unroll
    for (int j = 0; j < 2; ++j) {
      int x = x0 + wc * 32 + j * 16 + llo;
      int xm = x ? DIM - x : 0;
#pragma unroll
      for (int q = 0; q < 4; ++q) {
        int tt = y0 + wr * 32 + i * 16 + lhi * 4 + q;
        int y = 2 * tt + par;
        int ym = y ? DIM - y : 0;
        float c1 = acc1[i][j][q], c2 = acc2[i][j][q];
        float vd = c1 + c2;
        float vs = c1 - c2;
        Cp[(size_t)y  * DIM + x]  = vd;
        Cp[(size_t)ym * DIM + xm] = vd;
        Cp[(size_t)y  * DIM + xm] = vs;
        Cp[(size_t)ym * DIM + x]  = vs;
      }
    }
  }
}

// ---------------------------------------------------------------------------
extern "C" void kernel_launch(void* const* d_in, const int* in_sizes, int n_in,
                              void* d_out, int out_size, void* d_ws, size_t ws_size,
                              hipStream_t stream) {
  const float* cls   = (const float*)d_in[0];
  const float* Wr    = (const float*)d_in[1];
  const float* br    = (const float*)d_in[2];
  const float* coeff = (const float*)d_in[3];
  const int*   lidx  = (const int*)d_in[4];
  float* out = (float*)d_out;

  char* ws = (char*)d_ws;
  int*    row_start = (int*)(ws + 0);           //    98,432
  float4* s_cv      = (float4*)(ws + 98944);    // 2,097,152 (ends 2,196,096)
  __hip_bfloat16* A  = (__hip_bfloat16*)(ws + 2196096);  // 589,824 (ends 2,785,920)
  __hip_bfloat16* BT = (__hip_bfloat16*)(ws + 2785920);  // 37,748,736 (~40.5 MB)

  prep_kernel<<<32 + 384, 256, 0, stream>>>(cls, Wr, br, coeff, lidx,
                                            row_start, s_cv, A);
  stage1_kernel<<<dim3(12, 2, NB), 512, 0, stream>>>(row_start, s_cv, BT);
  gemm_kernel<<<4 * NB + 1152, 256, 0, stream>>>(A, BT, row_start, s_cv, out);
}